// Round 7
// baseline (222.007 us; speedup 1.0000x reference)
//
#include <hip/hip_runtime.h>

typedef unsigned short u16;
typedef __attribute__((ext_vector_type(8))) short short8;
typedef __attribute__((ext_vector_type(4))) float f32x4;
typedef __attribute__((ext_vector_type(4))) unsigned short u16x4;
typedef __attribute__((ext_vector_type(4))) float float4v;

__device__ __forceinline__ u16 f2bf(float f) {
  union { float f; unsigned u; } v; v.f = f;
  unsigned r = v.u + 0x7FFFu + ((v.u >> 16) & 1u);
  return (u16)(r >> 16);
}

__device__ __forceinline__ void gload16(const void* g, void* l) {
  __builtin_amdgcn_global_load_lds(
      (const __attribute__((address_space(1))) unsigned int*)g,
      (__attribute__((address_space(3))) unsigned int*)l, 16, 0, 0);
}

// ---------------- conversion kernels ----------------

__global__ __launch_bounds__(256) void kconv_x(const float* __restrict__ X,
                                               u16* __restrict__ Xb) {
  size_t i = ((size_t)blockIdx.x * 256 + threadIdx.x) * 4;
  float4v v = *(const float4v*)(X + i);
  u16x4 o;
  o.x = f2bf(v.x); o.y = f2bf(v.y); o.z = f2bf(v.z); o.w = f2bf(v.w);
  *(u16x4*)(Xb + i) = o;
}

__global__ __launch_bounds__(256) void kconv_wt(const float* __restrict__ Wq,
                                                const float* __restrict__ Wk,
                                                const float* __restrict__ Wv,
                                                u16* __restrict__ Wt) {
  __shared__ float tile[32][33];
  const float* W = blockIdx.z == 0 ? Wq : (blockIdx.z == 1 ? Wk : Wv);
  u16* O = Wt + (size_t)blockIdx.z * 1024 * 1024;
  int tx = threadIdx.x, ty = threadIdx.y;
  int n0 = blockIdx.x * 32, k0 = blockIdx.y * 32;
#pragma unroll
  for (int r = 0; r < 32; r += 8)
    tile[ty + r][tx] = W[(size_t)(k0 + ty + r) * 1024 + n0 + tx];
  __syncthreads();
#pragma unroll
  for (int r = 0; r < 32; r += 8)
    O[(size_t)(n0 + ty + r) * 1024 + k0 + tx] = f2bf(tile[tx][ty + r]);
}

// ---------------- GEMM core (m97 structure) ----------------
// C[128x128] += A[M,K] * Bt[N,K]^T  ; BK=32, 256 threads = 4 waves (2x2),
// each wave 64x64 as 4x4 frags of mfma_f32_16x16x32_bf16.
__device__ __forceinline__ void gemm_inner(const u16* __restrict__ A,
                                           const u16* __restrict__ B,
                                           int lda, int ldb,
                                           int rowBase, int colBase, int kIters,
                                           u16* As, u16* Bs, f32x4 acc[4][4]) {
  const int t = threadIdx.x;
  const int wid = t >> 6, lane = t & 63;
  const int wm = wid >> 1, wn = wid & 1;
  const int lrow = lane & 15, kseg = (lane >> 4) * 8;
  const u16* ga = A + (size_t)(rowBase + (t >> 2)) * lda + ((t & 3) * 8);
  const u16* gb = B + (size_t)(colBase + (t >> 2)) * ldb + ((t & 3) * 8);
  u16* la0 = As + wid * 512;
  u16* la1 = As + 2048 + wid * 512;
  u16* lb0 = Bs + wid * 512;
  u16* lb1 = Bs + 2048 + wid * 512;
  const size_t a64 = (size_t)64 * lda, b64 = (size_t)64 * ldb;

  for (int kt = 0; kt < kIters; ++kt) {
    const int k0 = kt * 32;
    gload16(ga + k0, la0);
    gload16(ga + a64 + k0, la1);
    gload16(gb + k0, lb0);
    gload16(gb + b64 + k0, lb1);
    __syncthreads();
    short8 a[4], b[4];
#pragma unroll
    for (int mi = 0; mi < 4; mi++)
      a[mi] = *(const short8*)(As + (wm * 64 + mi * 16 + lrow) * 32 + kseg);
#pragma unroll
    for (int ni = 0; ni < 4; ni++)
      b[ni] = *(const short8*)(Bs + (wn * 64 + ni * 16 + lrow) * 32 + kseg);
#pragma unroll
    for (int mi = 0; mi < 4; mi++)
#pragma unroll
      for (int ni = 0; ni < 4; ni++)
        acc[mi][ni] = __builtin_amdgcn_mfma_f32_16x16x32_bf16(
            a[mi], b[ni], acc[mi][ni], 0, 0, 0);
    __syncthreads();
  }
}

// ---------------- QKV projection (persistent x2) ----------------
// 768 blocks = 3/CU (12 waves/CU). Block: fixed rowTile (A panel L2-hot),
// 2 consecutive cz tiles. XCD owns 8 rowTiles -> 2MB X panel per-XCD L2.
__global__ __launch_bounds__(256) void kqkv(const u16* __restrict__ Xb,
                                            const u16* __restrict__ Wt,
                                            u16* __restrict__ Qb,
                                            u16* __restrict__ Kb,
                                            u16* __restrict__ Vt) {
  __shared__ __align__(16) u16 As[4096];
  __shared__ __align__(16) u16 Bs[4096];
  const int bidx = blockIdx.x;             // 0..767
  const int xcd = bidx & 7, i = bidx >> 3; // i 0..95
  const int rloc = i & 7, czg = i >> 3;    // rowTile fix; czg 0..11
  const int rowTile = xcd * 8 + rloc;      // 0..63
  const int rowBase = rowTile * 128;

  const int t = threadIdx.x, wid = t >> 6, lane = t & 63;
  const int wm = wid >> 1, wn = wid & 1;

  for (int jj = 0; jj < 2; ++jj) {
    const int cz = czg * 2 + jj;           // 0..23
    const int z = cz >> 3, colTile = cz & 7;
    const int colBase = colTile * 128;

    f32x4 acc[4][4];
#pragma unroll
    for (int a = 0; a < 4; a++)
#pragma unroll
      for (int b = 0; b < 4; b++) acc[a][b] = f32x4{0.f, 0.f, 0.f, 0.f};

    const u16* Bt = Wt + (size_t)z * 1024 * 1024;
    gemm_inner(Xb, Bt, 1024, 1024, rowBase, colBase, 32, As, Bs, acc);

    const int r0 = rowBase + wm * 64 + ((lane >> 4) * 4);
    const int c0 = colBase + wn * 64 + (lane & 15);
    if (z < 2) {
      u16* O = z ? Kb : Qb;
#pragma unroll
      for (int mi = 0; mi < 4; mi++) {
        int r = r0 + mi * 16;
#pragma unroll
        for (int ni = 0; ni < 4; ni++) {
          int c = c0 + ni * 16;
#pragma unroll
          for (int j = 0; j < 4; j++)
            O[(size_t)(r + j) * 1024 + c] = f2bf(acc[mi][ni][j]);
        }
      }
    } else {
#pragma unroll
      for (int mi = 0; mi < 4; mi++) {
        int s0 = r0 + mi * 16;             // global row (= b*2048 + s)
        int bb = s0 >> 11, sl = s0 & 2047;
#pragma unroll
        for (int ni = 0; ni < 4; ni++) {
          int d = c0 + ni * 16;
          u16x4 pk;
          pk.x = f2bf(acc[mi][ni][0]);
          pk.y = f2bf(acc[mi][ni][1]);
          pk.z = f2bf(acc[mi][ni][2]);
          pk.w = f2bf(acc[mi][ni][3]);
          *(u16x4*)(Vt + ((size_t)bb * 1024 + d) * 2048 + sl) = pk;
        }
      }
    }
  }
}

// ---------------- scores = Q K^T / 32 (persistent x2, lower-tri) ------------
// 544 tri-tiles (136 x 4 batches), 68 per XCD, 2 per block -> 272 blocks.
__global__ __launch_bounds__(256) void kscores(const u16* __restrict__ Q,
                                               const u16* __restrict__ K,
                                               float* __restrict__ Sc) {
  __shared__ __align__(16) u16 As[4096];
  __shared__ __align__(16) u16 Bs[4096];
  const int bidx = blockIdx.x;               // 0..271
  const int xcd = bidx & 7, ii = bidx >> 3;  // ii 0..33
  const int t = threadIdx.x, wid = t >> 6, lane = t & 63;
  const int wm = wid >> 1, wn = wid & 1;

  for (int k = 0; k < 2; ++k) {
    const int e = ii * 2 + k;                // 0..67
    const int bt = e / 17, idx = e % 17;     // batch, per-XCD tri slot
    const int tid = xcd * 17 + idx;          // 0..135
    int tr = (int)((sqrtf(8.f * tid + 1.f) - 1.f) * 0.5f);
    while ((tr + 1) * (tr + 2) / 2 <= tid) ++tr;
    while (tr * (tr + 1) / 2 > tid) --tr;
    const int tc = tid - tr * (tr + 1) / 2;

    f32x4 acc[4][4];
#pragma unroll
    for (int a = 0; a < 4; a++)
#pragma unroll
      for (int b = 0; b < 4; b++) acc[a][b] = f32x4{0.f, 0.f, 0.f, 0.f};

    const u16* Qp = Q + (size_t)bt * 2048 * 1024;
    const u16* Kp = K + (size_t)bt * 2048 * 1024;
    gemm_inner(Qp, Kp, 1024, 1024, tr * 128, tc * 128, 32, As, Bs, acc);

    float* S = Sc + (size_t)bt * 2048 * 2048;
    const int r0 = tr * 128 + wm * 64 + ((lane >> 4) * 4);
    const int c0 = tc * 128 + wn * 64 + (lane & 15);
#pragma unroll
    for (int mi = 0; mi < 4; mi++) {
      int r = r0 + mi * 16;
#pragma unroll
      for (int ni = 0; ni < 4; ni++) {
        int c = c0 + ni * 16;
#pragma unroll
        for (int j = 0; j < 4; j++)
          S[(size_t)(r + j) * 2048 + c] = acc[mi][ni][j] * 0.03125f;
      }
    }
  }
}

// ---------------- row softmax -> P bf16 (4 rows per block) ----------------
__global__ __launch_bounds__(256) void ksoftmax(const float* __restrict__ Sc,
                                                u16* __restrict__ P) {
  const int b = blockIdx.y;
  __shared__ float srow[2048];
  __shared__ float red[4];
  const int t = threadIdx.x, lane = t & 63, wid = t >> 6;

  for (int r = 0; r < 4; ++r) {
    const int i = blockIdx.x * 4 + r;
    const int nv = i + 1;
    const int nceil = ((i >> 7) + 1) << 7;
    const float* S = Sc + ((size_t)b * 2048 + i) * 2048;
    u16* Pr = P + ((size_t)b * 2048 + i) * 2048;

    float lm = -3.0e38f;
    for (int j = t; j < nv; j += 256) {
      float v = S[j];
      srow[j] = v;
      lm = fmaxf(lm, v);
    }
#pragma unroll
    for (int o = 32; o > 0; o >>= 1) lm = fmaxf(lm, __shfl_down(lm, o));
    if (lane == 0) red[wid] = lm;
    __syncthreads();
    const float m = fmaxf(fmaxf(red[0], red[1]), fmaxf(red[2], red[3]));

    float ls = 0.f;
    for (int j = t; j < nv; j += 256) {
      float e = __expf(srow[j] - m);
      srow[j] = e;
      ls += e;
    }
#pragma unroll
    for (int o = 32; o > 0; o >>= 1) ls += __shfl_down(ls, o);
    __syncthreads();
    if (lane == 0) red[wid] = ls;
    __syncthreads();
    const float inv = 1.f / (red[0] + red[1] + red[2] + red[3]);

    for (int j = t; j < nv; j += 256) Pr[j] = f2bf(srow[j] * inv);
    for (int j = nv + t; j < nceil; j += 256) Pr[j] = 0;
    __syncthreads();  // guard srow/red reuse next row
  }
}

// ---------------- context = P V (128^2, causal-truncated K) ----------------
__global__ __launch_bounds__(256) void kpv(const u16* __restrict__ P,
                                           const u16* __restrict__ Vt,
                                           float* __restrict__ Out) {
  const int x = blockIdx.x, b = blockIdx.y;
  const int xcd = x & 7, idx = x >> 3;       // idx 0..15
  const int tr = (idx < 8) ? xcd : (15 - xcd);
  const int col = idx & 7;

  __shared__ __align__(16) u16 As[4096];
  __shared__ __align__(16) u16 Bs[4096];
  const f32x4 z4 = {0.f, 0.f, 0.f, 0.f};
  f32x4 acc[4][4];
#pragma unroll
  for (int i = 0; i < 4; i++)
#pragma unroll
    for (int j = 0; j < 4; j++) acc[i][j] = z4;

  const u16* Pp = P + (size_t)b * 2048 * 2048;
  const u16* Vp = Vt + (size_t)b * 1024 * 2048;
  gemm_inner(Pp, Vp, 2048, 2048, tr * 128, col * 128, (tr + 1) * 4, As, Bs, acc);

  float* Ob = Out + (size_t)b * 2048 * 1024;
  const int t = threadIdx.x, wid = t >> 6, lane = t & 63;
  const int wm = wid >> 1, wn = wid & 1;
  const int r0 = tr * 128 + wm * 64 + ((lane >> 4) * 4);
  const int c0 = col * 128 + wn * 64 + (lane & 15);
#pragma unroll
  for (int mi = 0; mi < 4; mi++) {
    int r = r0 + mi * 16;
#pragma unroll
    for (int ni = 0; ni < 4; ni++) {
      int c = c0 + ni * 16;
#pragma unroll
      for (int j = 0; j < 4; j++)
        Ob[(size_t)(r + j) * 1024 + c] = acc[mi][ni][j];
    }
  }
}

extern "C" void kernel_launch(void* const* d_in, const int* in_sizes, int n_in,
                              void* d_out, int out_size, void* d_ws,
                              size_t ws_size, hipStream_t stream) {
  const float* X = (const float*)d_in[0];
  const float* Wq = (const float*)d_in[1];
  const float* Wk = (const float*)d_in[2];
  const float* Wv = (const float*)d_in[3];
  float* Out = (float*)d_out;

  char* ws = (char*)d_ws;
  u16* Xb = (u16*)(ws);                     // 16 MB  bf16 X
  u16* Wt = (u16*)(ws + 16777216);          //  6 MB  bf16 W^T x3
  u16* Qb = (u16*)(ws + 23068672);          // 16 MB
  u16* Kb = (u16*)(ws + 39845888);          // 16 MB
  u16* Vt = (u16*)(ws + 56623104);          // 16 MB  V transposed per batch
  float* Sc = (float*)(ws + 73400320);      // 64 MB  fp32 scores
  u16* P = (u16*)(ws + 140509184);          // 32 MB  bf16 probs

  kconv_x<<<8192, 256, 0, stream>>>(X, Xb);
  kconv_wt<<<dim3(32, 32, 3), dim3(32, 8), 0, stream>>>(Wq, Wk, Wv, Wt);
  kqkv<<<768, 256, 0, stream>>>(Xb, Wt, Qb, Kb, Vt);
  kscores<<<272, 256, 0, stream>>>(Qb, Kb, Sc);
  ksoftmax<<<dim3(512, 4), 256, 0, stream>>>(Sc, P);
  kpv<<<dim3(128, 4), 256, 0, stream>>>(P, Vt, Out);
}

// Round 8
// 172.390 us; speedup vs baseline: 1.2878x; 1.2878x over previous
//
#include <hip/hip_runtime.h>

typedef unsigned short u16;
typedef __attribute__((ext_vector_type(8))) short short8;
typedef __attribute__((ext_vector_type(4))) float f32x4;
typedef __attribute__((ext_vector_type(4))) unsigned short u16x4;
typedef __attribute__((ext_vector_type(4))) float float4v;

__device__ __forceinline__ u16 f2bf(float f) {
  union { float f; unsigned u; } v; v.f = f;
  unsigned r = v.u + 0x7FFFu + ((v.u >> 16) & 1u);
  return (u16)(r >> 16);
}

__device__ __forceinline__ void gload16(const void* g, void* l) {
  __builtin_amdgcn_global_load_lds(
      (const __attribute__((address_space(1))) unsigned int*)g,
      (__attribute__((address_space(3))) unsigned int*)l, 16, 0, 0);
}

// ---------------- conversion kernels ----------------

// X fp32 [8192,1024] -> bf16 linear
__global__ __launch_bounds__(256) void kconv_x(const float* __restrict__ X,
                                               u16* __restrict__ Xb) {
  size_t i = ((size_t)blockIdx.x * 256 + threadIdx.x) * 4;
  float4v v = *(const float4v*)(X + i);
  u16x4 o;
  o.x = f2bf(v.x); o.y = f2bf(v.y); o.z = f2bf(v.z); o.w = f2bf(v.w);
  *(u16x4*)(Xb + i) = o;
}

// W fp32 [K=1024][N=1024] -> Wt bf16 [N][K], z selects Wq/Wk/Wv
__global__ __launch_bounds__(256) void kconv_wt(const float* __restrict__ Wq,
                                                const float* __restrict__ Wk,
                                                const float* __restrict__ Wv,
                                                u16* __restrict__ Wt) {
  __shared__ float tile[32][33];
  const float* W = blockIdx.z == 0 ? Wq : (blockIdx.z == 1 ? Wk : Wv);
  u16* O = Wt + (size_t)blockIdx.z * 1024 * 1024;
  int tx = threadIdx.x, ty = threadIdx.y;
  int n0 = blockIdx.x * 32, k0 = blockIdx.y * 32;
#pragma unroll
  for (int r = 0; r < 32; r += 8)
    tile[ty + r][tx] = W[(size_t)(k0 + ty + r) * 1024 + n0 + tx];
  __syncthreads();
#pragma unroll
  for (int r = 0; r < 32; r += 8)
    O[(size_t)(n0 + ty + r) * 1024 + k0 + tx] = f2bf(tile[tx][ty + r]);
}

// ---------------- GEMM core (m97 structure) ----------------
// C[128x128] += A[M,K] * Bt[N,K]^T  ; BK=32, 256 threads = 4 waves (2x2),
// each wave 64x64 as 4x4 frags of mfma_f32_16x16x32_bf16.
__device__ __forceinline__ void gemm_inner(const u16* __restrict__ A,
                                           const u16* __restrict__ B,
                                           int lda, int ldb,
                                           int rowBase, int colBase, int kIters,
                                           u16* As, u16* Bs, f32x4 acc[4][4]) {
  const int t = threadIdx.x;
  const int wid = t >> 6, lane = t & 63;
  const int wm = wid >> 1, wn = wid & 1;
  const int lrow = lane & 15, kseg = (lane >> 4) * 8;
  const u16* ga = A + (size_t)(rowBase + (t >> 2)) * lda + ((t & 3) * 8);
  const u16* gb = B + (size_t)(colBase + (t >> 2)) * ldb + ((t & 3) * 8);
  u16* la0 = As + wid * 512;
  u16* la1 = As + 2048 + wid * 512;
  u16* lb0 = Bs + wid * 512;
  u16* lb1 = Bs + 2048 + wid * 512;
  const size_t a64 = (size_t)64 * lda, b64 = (size_t)64 * ldb;

  for (int kt = 0; kt < kIters; ++kt) {
    const int k0 = kt * 32;
    gload16(ga + k0, la0);
    gload16(ga + a64 + k0, la1);
    gload16(gb + k0, lb0);
    gload16(gb + b64 + k0, lb1);
    __syncthreads();
    short8 a[4], b[4];
#pragma unroll
    for (int mi = 0; mi < 4; mi++)
      a[mi] = *(const short8*)(As + (wm * 64 + mi * 16 + lrow) * 32 + kseg);
#pragma unroll
    for (int ni = 0; ni < 4; ni++)
      b[ni] = *(const short8*)(Bs + (wn * 64 + ni * 16 + lrow) * 32 + kseg);
#pragma unroll
    for (int mi = 0; mi < 4; mi++)
#pragma unroll
      for (int ni = 0; ni < 4; ni++)
        acc[mi][ni] = __builtin_amdgcn_mfma_f32_16x16x32_bf16(
            a[mi], b[ni], acc[mi][ni], 0, 0, 0);
    __syncthreads();
  }
}

// ---------------- QKV projection ----------------
// 1536 linear blocks, XCD-chunked: XCD owns 8 row-tiles, (col,z) outer,
// row inner -> X tile (2MB) resident in per-XCD L2, reused 24x.
// __launch_bounds__(256,3): force total regs <=168 -> 3 blocks/CU resident.
__global__ __launch_bounds__(256, 3) void kqkv(const u16* __restrict__ Xb,
                                               const u16* __restrict__ Wt,
                                               u16* __restrict__ Qb,
                                               u16* __restrict__ Kb,
                                               u16* __restrict__ Vt) {
  __shared__ __align__(16) u16 As[4096];
  __shared__ __align__(16) u16 Bs[4096];
  const f32x4 z4 = {0.f, 0.f, 0.f, 0.f};
  f32x4 acc[4][4];
#pragma unroll
  for (int i = 0; i < 4; i++)
#pragma unroll
    for (int j = 0; j < 4; j++) acc[i][j] = z4;

  const int l = blockIdx.x;
  const int xcd = l & 7, idx = l >> 3;    // idx 0..191
  const int cz = idx >> 3, rloc = idx & 7; // cz 0..23 outer, row inner
  const int rowTile = xcd * 8 + rloc;      // 0..63
  const int z = cz >> 3, colTile = cz & 7; // z 0..2, col 0..7

  const int rowBase = rowTile * 128, colBase = colTile * 128;
  const u16* Bt = Wt + (size_t)z * 1024 * 1024;
  gemm_inner(Xb, Bt, 1024, 1024, rowBase, colBase, 32, As, Bs, acc);

  const int t = threadIdx.x, wid = t >> 6, lane = t & 63;
  const int wm = wid >> 1, wn = wid & 1;
  const int r0 = rowBase + wm * 64 + ((lane >> 4) * 4);
  const int c0 = colBase + wn * 64 + (lane & 15);
  if (z < 2) {
    u16* O = z ? Kb : Qb;
#pragma unroll
    for (int mi = 0; mi < 4; mi++) {
      int r = r0 + mi * 16;
#pragma unroll
      for (int ni = 0; ni < 4; ni++) {
        int c = c0 + ni * 16;
#pragma unroll
        for (int j = 0; j < 4; j++)
          O[(size_t)(r + j) * 1024 + c] = f2bf(acc[mi][ni][j]);
      }
    }
  } else {
#pragma unroll
    for (int mi = 0; mi < 4; mi++) {
      int s0 = r0 + mi * 16;          // global row index (= b*2048 + s)
      int bb = s0 >> 11, sl = s0 & 2047;
#pragma unroll
      for (int ni = 0; ni < 4; ni++) {
        int d = c0 + ni * 16;
        u16x4 pk;
        pk.x = f2bf(acc[mi][ni][0]);
        pk.y = f2bf(acc[mi][ni][1]);
        pk.z = f2bf(acc[mi][ni][2]);
        pk.w = f2bf(acc[mi][ni][3]);
        *(u16x4*)(Vt + ((size_t)bb * 1024 + d) * 2048 + sl) = pk;
      }
    }
  }
}

// ---------------- scores = Q K^T / 32 (lower-tri tiles only) ----------------
// 136 tri-tiles per batch, 17 per XCD (equal work, contiguous tr ranges).
__global__ __launch_bounds__(256, 3) void kscores(const u16* __restrict__ Q,
                                                  const u16* __restrict__ K,
                                                  float* __restrict__ Sc) {
  const int x = blockIdx.x, b = blockIdx.y;
  const int xcd = x & 7, idx = x >> 3;   // idx 0..16
  const int tid = xcd * 17 + idx;        // 0..135
  int tr = (int)((sqrtf(8.f * tid + 1.f) - 1.f) * 0.5f);
  while ((tr + 1) * (tr + 2) / 2 <= tid) ++tr;
  while (tr * (tr + 1) / 2 > tid) --tr;
  const int tc = tid - tr * (tr + 1) / 2;

  __shared__ __align__(16) u16 As[4096];
  __shared__ __align__(16) u16 Bs[4096];
  const f32x4 z4 = {0.f, 0.f, 0.f, 0.f};
  f32x4 acc[4][4];
#pragma unroll
  for (int i = 0; i < 4; i++)
#pragma unroll
    for (int j = 0; j < 4; j++) acc[i][j] = z4;

  const u16* Qp = Q + (size_t)b * 2048 * 1024;
  const u16* Kp = K + (size_t)b * 2048 * 1024;
  gemm_inner(Qp, Kp, 1024, 1024, tr * 128, tc * 128, 32, As, Bs, acc);

  float* S = Sc + (size_t)b * 2048 * 2048;
  const int t = threadIdx.x, wid = t >> 6, lane = t & 63;
  const int wm = wid >> 1, wn = wid & 1;
  const int r0 = tr * 128 + wm * 64 + ((lane >> 4) * 4);
  const int c0 = tc * 128 + wn * 64 + (lane & 15);
#pragma unroll
  for (int mi = 0; mi < 4; mi++) {
    int r = r0 + mi * 16;
#pragma unroll
    for (int ni = 0; ni < 4; ni++) {
      int c = c0 + ni * 16;
#pragma unroll
      for (int j = 0; j < 4; j++)
        S[(size_t)(r + j) * 2048 + c] = acc[mi][ni][j] * 0.03125f;
    }
  }
}

// ---------------- row softmax -> P bf16 (zero-filled to tile ceiling) -------
__global__ __launch_bounds__(256) void ksoftmax(const float* __restrict__ Sc,
                                                u16* __restrict__ P) {
  const int i = blockIdx.x, b = blockIdx.y;
  const int nv = i + 1;
  const int nceil = ((i >> 7) + 1) << 7;
  const float* S = Sc + ((size_t)b * 2048 + i) * 2048;
  u16* Pr = P + ((size_t)b * 2048 + i) * 2048;
  __shared__ float srow[2048];
  __shared__ float red[4];
  const int t = threadIdx.x, lane = t & 63, wid = t >> 6;

  float lm = -3.0e38f;
  for (int j = t; j < nv; j += 256) {
    float v = S[j];
    srow[j] = v;
    lm = fmaxf(lm, v);
  }
#pragma unroll
  for (int o = 32; o > 0; o >>= 1) lm = fmaxf(lm, __shfl_down(lm, o));
  if (lane == 0) red[wid] = lm;
  __syncthreads();
  const float m = fmaxf(fmaxf(red[0], red[1]), fmaxf(red[2], red[3]));

  float ls = 0.f;
  for (int j = t; j < nv; j += 256) {
    float e = __expf(srow[j] - m);
    srow[j] = e;
    ls += e;
  }
#pragma unroll
  for (int o = 32; o > 0; o >>= 1) ls += __shfl_down(ls, o);
  __syncthreads();
  if (lane == 0) red[wid] = ls;
  __syncthreads();
  const float inv = 1.f / (red[0] + red[1] + red[2] + red[3]);

  for (int j = t; j < nv; j += 256) Pr[j] = f2bf(srow[j] * inv);
  for (int j = nv + t; j < nceil; j += 256) Pr[j] = 0;
}

// ---------------- context = P V  (K-loop truncated causally) ----------------
// 128 blocks/batch; XCD pairs tr=xcd with tr=15-xcd -> equal causal work/XCD.
__global__ __launch_bounds__(256, 3) void kpv(const u16* __restrict__ P,
                                              const u16* __restrict__ Vt,
                                              float* __restrict__ Out) {
  const int x = blockIdx.x, b = blockIdx.y;
  const int xcd = x & 7, idx = x >> 3;       // idx 0..15
  const int tr = (idx < 8) ? xcd : (15 - xcd);
  const int col = idx & 7;

  __shared__ __align__(16) u16 As[4096];
  __shared__ __align__(16) u16 Bs[4096];
  const f32x4 z4 = {0.f, 0.f, 0.f, 0.f};
  f32x4 acc[4][4];
#pragma unroll
  for (int i = 0; i < 4; i++)
#pragma unroll
    for (int j = 0; j < 4; j++) acc[i][j] = z4;

  const u16* Pp = P + (size_t)b * 2048 * 2048;
  const u16* Vp = Vt + (size_t)b * 1024 * 2048;
  gemm_inner(Pp, Vp, 2048, 2048, tr * 128, col * 128, (tr + 1) * 4, As, Bs, acc);

  float* Ob = Out + (size_t)b * 2048 * 1024;
  const int t = threadIdx.x, wid = t >> 6, lane = t & 63;
  const int wm = wid >> 1, wn = wid & 1;
  const int r0 = tr * 128 + wm * 64 + ((lane >> 4) * 4);
  const int c0 = col * 128 + wn * 64 + (lane & 15);
#pragma unroll
  for (int mi = 0; mi < 4; mi++) {
    int r = r0 + mi * 16;
#pragma unroll
    for (int ni = 0; ni < 4; ni++) {
      int c = c0 + ni * 16;
#pragma unroll
      for (int j = 0; j < 4; j++)
        Ob[(size_t)(r + j) * 1024 + c] = acc[mi][ni][j];
    }
  }
}

extern "C" void kernel_launch(void* const* d_in, const int* in_sizes, int n_in,
                              void* d_out, int out_size, void* d_ws,
                              size_t ws_size, hipStream_t stream) {
  const float* X = (const float*)d_in[0];
  const float* Wq = (const float*)d_in[1];
  const float* Wk = (const float*)d_in[2];
  const float* Wv = (const float*)d_in[3];
  float* Out = (float*)d_out;

  char* ws = (char*)d_ws;
  u16* Xb = (u16*)(ws);                     // 16 MB  bf16 X
  u16* Wt = (u16*)(ws + 16777216);          //  6 MB  bf16 W^T x3
  u16* Qb = (u16*)(ws + 23068672);          // 16 MB
  u16* Kb = (u16*)(ws + 39845888);          // 16 MB
  u16* Vt = (u16*)(ws + 56623104);          // 16 MB  V transposed per batch
  float* Sc = (float*)(ws + 73400320);      // 64 MB  fp32 scores
  u16* P = (u16*)(ws + 140509184);          // 32 MB  bf16 probs

  kconv_x<<<8192, 256, 0, stream>>>(X, Xb);
  kconv_wt<<<dim3(32, 32, 3), dim3(32, 8), 0, stream>>>(Wq, Wk, Wv, Wt);
  kqkv<<<1536, 256, 0, stream>>>(Xb, Wt, Qb, Kb, Vt);
  kscores<<<dim3(136, 4), 256, 0, stream>>>(Qb, Kb, Sc);
  ksoftmax<<<dim3(2048, 4), 256, 0, stream>>>(Sc, P);
  kpv<<<dim3(128, 4), 256, 0, stream>>>(P, Vt, Out);
}

// Round 9
// 147.683 us; speedup vs baseline: 1.5033x; 1.1673x over previous
//
#include <hip/hip_runtime.h>

typedef unsigned short u16;
typedef __attribute__((ext_vector_type(8))) short short8;
typedef __attribute__((ext_vector_type(4))) float f32x4;
typedef __attribute__((ext_vector_type(4))) unsigned short u16x4;
typedef __attribute__((ext_vector_type(4))) float float4v;

__device__ __forceinline__ u16 f2bf(float f) {
  union { float f; unsigned u; } v; v.f = f;
  unsigned r = v.u + 0x7FFFu + ((v.u >> 16) & 1u);
  return (u16)(r >> 16);
}

__device__ __forceinline__ void gload16(const void* g, void* l) {
  __builtin_amdgcn_global_load_lds(
      (const __attribute__((address_space(1))) unsigned int*)g,
      (__attribute__((address_space(3))) unsigned int*)l, 16, 0, 0);
}

// ---------------- merged conversion kernel ----------------
// bx < 8192: X fp32 -> bf16 linear.  bx >= 8192: W -> Wt bf16 transposed.
__global__ __launch_bounds__(256) void kconv(const float* __restrict__ X,
                                             const float* __restrict__ Wq,
                                             const float* __restrict__ Wk,
                                             const float* __restrict__ Wv,
                                             u16* __restrict__ Xb,
                                             u16* __restrict__ Wt) {
  __shared__ float tile[32][33];
  const int bx = blockIdx.x;
  if (bx < 8192) {
    size_t i = ((size_t)bx * 256 + threadIdx.x) * 4;
    float4v v = *(const float4v*)(X + i);
    u16x4 o;
    o.x = f2bf(v.x); o.y = f2bf(v.y); o.z = f2bf(v.z); o.w = f2bf(v.w);
    *(u16x4*)(Xb + i) = o;
  } else {
    const int l = bx - 8192;          // 0..3071
    const int z = l >> 10;            // 0..2
    const int rem = l & 1023;         // 32x32 tiles
    const int n0 = (rem & 31) * 32, k0 = (rem >> 5) * 32;
    const float* W = z == 0 ? Wq : (z == 1 ? Wk : Wv);
    u16* O = Wt + (size_t)z * 1024 * 1024;
    const int tx = threadIdx.x & 31, ty = threadIdx.x >> 5;  // 32 x 8
#pragma unroll
    for (int r = 0; r < 32; r += 8)
      tile[ty + r][tx] = W[(size_t)(k0 + ty + r) * 1024 + n0 + tx];
    __syncthreads();
#pragma unroll
    for (int r = 0; r < 32; r += 8)
      O[(size_t)(n0 + ty + r) * 1024 + k0 + tx] = f2bf(tile[tx][ty + r]);
  }
}

// ---------------- GEMM core: BK=64, both-sides XOR swizzle ----------------
// C[128x128] += A[M,K] * Bt[N,K]^T ; 256 thr = 4 waves (2x2), 64x64/wave.
// LDS tiles [128][64] u16 (16KB each). Swizzle: LDS[row][s] holds global
// slot s^(row&7) (16B slots). gload_lds dest linear; source pre-swizzled;
// ds_read applies the same XOR -> worst 2-way bank aliasing (free).
__device__ __forceinline__ void stage64(const u16* __restrict__ pan, int ld,
                                        int k0, u16* dst, int t) {
  const int rb = t >> 3;                     // 0..31
  const int sw = ((t & 7) ^ (rb & 7)) * 8;   // pre-swizzled source slot
  const int ds = (t & 7) * 8;                // linear LDS slot
#pragma unroll
  for (int j = 0; j < 4; ++j) {
    const int row = j * 32 + rb;
    gload16(pan + (size_t)row * ld + k0 + sw, dst + row * 64 + ds);
  }
}

__device__ __forceinline__ void gemm64(const u16* __restrict__ A,
                                       const u16* __restrict__ B,
                                       int lda, int ldb,
                                       int rowBase, int colBase, int kIters,
                                       u16* As, u16* Bs, f32x4 acc[4][4]) {
  const int t = threadIdx.x;
  const int wid = t >> 6, lane = t & 63;
  const int wm = wid >> 1, wn = wid & 1;
  const int l15 = lane & 15;
  const int sw = l15 & 7;
  const int sl = lane >> 4;                  // 0..3
  const int s0 = ((sl    ) ^ sw) * 8;        // k 0..31 slot (u16 offset)
  const int s1 = ((sl + 4) ^ sw) * 8;        // k 32..63 slot
  const u16* ga = A + (size_t)rowBase * lda;
  const u16* gb = B + (size_t)colBase * ldb;

  for (int kt = 0; kt < kIters; ++kt) {
    const int k0 = kt * 64;
    stage64(ga, lda, k0, As, t);
    stage64(gb, ldb, k0, Bs, t);
    __syncthreads();
#pragma unroll
    for (int h = 0; h < 2; ++h) {
      const int so = h ? s1 : s0;
      short8 a[4], b[4];
#pragma unroll
      for (int mi = 0; mi < 4; mi++)
        a[mi] = *(const short8*)(As + (wm * 64 + mi * 16 + l15) * 64 + so);
#pragma unroll
      for (int ni = 0; ni < 4; ni++)
        b[ni] = *(const short8*)(Bs + (wn * 64 + ni * 16 + l15) * 64 + so);
#pragma unroll
      for (int mi = 0; mi < 4; mi++)
#pragma unroll
        for (int ni = 0; ni < 4; ni++)
          acc[mi][ni] = __builtin_amdgcn_mfma_f32_16x16x32_bf16(
              a[mi], b[ni], acc[mi][ni], 0, 0, 0);
    }
    __syncthreads();
  }
}

// ---------------- QKV projection ----------------
// 1536 blocks, XCD-chunked: XCD owns 8 row-tiles, (col,z) outer, row inner.
__global__ __launch_bounds__(256, 3) void kqkv(const u16* __restrict__ Xb,
                                               const u16* __restrict__ Wt,
                                               u16* __restrict__ Qb,
                                               u16* __restrict__ Kb,
                                               u16* __restrict__ Vt) {
  __shared__ __align__(16) u16 As[128 * 64];
  __shared__ __align__(16) u16 Bs[128 * 64];
  const f32x4 z4 = {0.f, 0.f, 0.f, 0.f};
  f32x4 acc[4][4];
#pragma unroll
  for (int i = 0; i < 4; i++)
#pragma unroll
    for (int j = 0; j < 4; j++) acc[i][j] = z4;

  const int l = blockIdx.x;
  const int xcd = l & 7, idx = l >> 3;     // idx 0..191
  const int cz = idx >> 3, rloc = idx & 7; // cz 0..23 outer, row inner
  const int rowTile = xcd * 8 + rloc;      // 0..63
  const int z = cz >> 3, colTile = cz & 7; // z 0..2, col 0..7

  const int rowBase = rowTile * 128, colBase = colTile * 128;
  const u16* Bt = Wt + (size_t)z * 1024 * 1024;
  gemm64(Xb, Bt, 1024, 1024, rowBase, colBase, 16, As, Bs, acc);

  const int t = threadIdx.x, wid = t >> 6, lane = t & 63;
  const int wm = wid >> 1, wn = wid & 1;
  const int r0 = rowBase + wm * 64 + ((lane >> 4) * 4);
  const int c0 = colBase + wn * 64 + (lane & 15);
  if (z < 2) {
    u16* O = z ? Kb : Qb;
#pragma unroll
    for (int mi = 0; mi < 4; mi++) {
      int r = r0 + mi * 16;
#pragma unroll
      for (int ni = 0; ni < 4; ni++) {
        int c = c0 + ni * 16;
#pragma unroll
        for (int j = 0; j < 4; j++)
          O[(size_t)(r + j) * 1024 + c] = f2bf(acc[mi][ni][j]);
      }
    }
  } else {
#pragma unroll
    for (int mi = 0; mi < 4; mi++) {
      int s0r = r0 + mi * 16;           // global row (= b*2048 + s)
      int bb = s0r >> 11, sl = s0r & 2047;
#pragma unroll
      for (int ni = 0; ni < 4; ni++) {
        int d = c0 + ni * 16;
        u16x4 pk;
        pk.x = f2bf(acc[mi][ni][0]);
        pk.y = f2bf(acc[mi][ni][1]);
        pk.z = f2bf(acc[mi][ni][2]);
        pk.w = f2bf(acc[mi][ni][3]);
        *(u16x4*)(Vt + ((size_t)bb * 1024 + d) * 2048 + sl) = pk;
      }
    }
  }
}

// ---------------- scores = Q K^T / 32 (lower-tri tiles only) ----------------
__global__ __launch_bounds__(256, 3) void kscores(const u16* __restrict__ Q,
                                                  const u16* __restrict__ K,
                                                  float* __restrict__ Sc) {
  const int x = blockIdx.x, b = blockIdx.y;
  const int xcd = x & 7, idx = x >> 3;   // idx 0..16
  const int tid = xcd * 17 + idx;        // 0..135
  int tr = (int)((sqrtf(8.f * tid + 1.f) - 1.f) * 0.5f);
  while ((tr + 1) * (tr + 2) / 2 <= tid) ++tr;
  while (tr * (tr + 1) / 2 > tid) --tr;
  const int tc = tid - tr * (tr + 1) / 2;

  __shared__ __align__(16) u16 As[128 * 64];
  __shared__ __align__(16) u16 Bs[128 * 64];
  const f32x4 z4 = {0.f, 0.f, 0.f, 0.f};
  f32x4 acc[4][4];
#pragma unroll
  for (int i = 0; i < 4; i++)
#pragma unroll
    for (int j = 0; j < 4; j++) acc[i][j] = z4;

  const u16* Qp = Q + (size_t)b * 2048 * 1024;
  const u16* Kp = K + (size_t)b * 2048 * 1024;
  gemm64(Qp, Kp, 1024, 1024, tr * 128, tc * 128, 16, As, Bs, acc);

  float* S = Sc + (size_t)b * 2048 * 2048;
  const int t = threadIdx.x, wid = t >> 6, lane = t & 63;
  const int wm = wid >> 1, wn = wid & 1;
  const int r0 = tr * 128 + wm * 64 + ((lane >> 4) * 4);
  const int c0 = tc * 128 + wn * 64 + (lane & 15);
#pragma unroll
  for (int mi = 0; mi < 4; mi++) {
    int r = r0 + mi * 16;
#pragma unroll
    for (int ni = 0; ni < 4; ni++) {
      int c = c0 + ni * 16;
#pragma unroll
      for (int j = 0; j < 4; j++)
        S[(size_t)(r + j) * 2048 + c] = acc[mi][ni][j] * 0.03125f;
    }
  }
}

// ---------------- row softmax -> P bf16 (zero-filled to tile ceiling) -------
__global__ __launch_bounds__(256) void ksoftmax(const float* __restrict__ Sc,
                                                u16* __restrict__ P) {
  const int i = blockIdx.x, b = blockIdx.y;
  const int nv = i + 1;
  const int nceil = ((i >> 7) + 1) << 7;
  const float* S = Sc + ((size_t)b * 2048 + i) * 2048;
  u16* Pr = P + ((size_t)b * 2048 + i) * 2048;
  __shared__ float srow[2048];
  __shared__ float red[4];
  const int t = threadIdx.x, lane = t & 63, wid = t >> 6;

  float lm = -3.0e38f;
  for (int j = t; j < nv; j += 256) {
    float v = S[j];
    srow[j] = v;
    lm = fmaxf(lm, v);
  }
#pragma unroll
  for (int o = 32; o > 0; o >>= 1) lm = fmaxf(lm, __shfl_down(lm, o));
  if (lane == 0) red[wid] = lm;
  __syncthreads();
  const float m = fmaxf(fmaxf(red[0], red[1]), fmaxf(red[2], red[3]));

  float ls = 0.f;
  for (int j = t; j < nv; j += 256) {
    float e = __expf(srow[j] - m);
    srow[j] = e;
    ls += e;
  }
#pragma unroll
  for (int o = 32; o > 0; o >>= 1) ls += __shfl_down(ls, o);
  __syncthreads();
  if (lane == 0) red[wid] = ls;
  __syncthreads();
  const float inv = 1.f / (red[0] + red[1] + red[2] + red[3]);

  for (int j = t; j < nv; j += 256) Pr[j] = f2bf(srow[j] * inv);
  for (int j = nv + t; j < nceil; j += 256) Pr[j] = 0;
}

// ---------------- context = P V  (K-loop truncated causally) ----------------
__global__ __launch_bounds__(256, 3) void kpv(const u16* __restrict__ P,
                                              const u16* __restrict__ Vt,
                                              float* __restrict__ Out) {
  const int x = blockIdx.x, b = blockIdx.y;
  const int xcd = x & 7, idx = x >> 3;       // idx 0..15
  const int tr = (idx < 8) ? xcd : (15 - xcd);
  const int col = idx & 7;

  __shared__ __align__(16) u16 As[128 * 64];
  __shared__ __align__(16) u16 Bs[128 * 64];
  const f32x4 z4 = {0.f, 0.f, 0.f, 0.f};
  f32x4 acc[4][4];
#pragma unroll
  for (int i = 0; i < 4; i++)
#pragma unroll
    for (int j = 0; j < 4; j++) acc[i][j] = z4;

  const u16* Pp = P + (size_t)b * 2048 * 2048;
  const u16* Vp = Vt + (size_t)b * 1024 * 2048;
  gemm64(Pp, Vp, 2048, 2048, tr * 128, col * 128, (tr + 1) * 2, As, Bs, acc);

  float* Ob = Out + (size_t)b * 2048 * 1024;
  const int t = threadIdx.x, wid = t >> 6, lane = t & 63;
  const int wm = wid >> 1, wn = wid & 1;
  const int r0 = tr * 128 + wm * 64 + ((lane >> 4) * 4);
  const int c0 = col * 128 + wn * 64 + (lane & 15);
#pragma unroll
  for (int mi = 0; mi < 4; mi++) {
    int r = r0 + mi * 16;
#pragma unroll
    for (int ni = 0; ni < 4; ni++) {
      int c = c0 + ni * 16;
#pragma unroll
      for (int j = 0; j < 4; j++)
        Ob[(size_t)(r + j) * 1024 + c] = acc[mi][ni][j];
    }
  }
}

extern "C" void kernel_launch(void* const* d_in, const int* in_sizes, int n_in,
                              void* d_out, int out_size, void* d_ws,
                              size_t ws_size, hipStream_t stream) {
  const float* X = (const float*)d_in[0];
  const float* Wq = (const float*)d_in[1];
  const float* Wk = (const float*)d_in[2];
  const float* Wv = (const float*)d_in[3];
  float* Out = (float*)d_out;

  char* ws = (char*)d_ws;
  u16* Xb = (u16*)(ws);                     // 16 MB  bf16 X
  u16* Wt = (u16*)(ws + 16777216);          //  6 MB  bf16 W^T x3
  u16* Qb = (u16*)(ws + 23068672);          // 16 MB
  u16* Kb = (u16*)(ws + 39845888);          // 16 MB
  u16* Vt = (u16*)(ws + 56623104);          // 16 MB  V transposed per batch
  float* Sc = (float*)(ws + 73400320);      // 64 MB  fp32 scores
  u16* P = (u16*)(ws + 140509184);          // 32 MB  bf16 probs

  kconv<<<11264, 256, 0, stream>>>(X, Wq, Wk, Wv, Xb, Wt);
  kqkv<<<1536, 256, 0, stream>>>(Xb, Wt, Qb, Kb, Vt);
  kscores<<<dim3(136, 4), 256, 0, stream>>>(Qb, Kb, Sc);
  ksoftmax<<<dim3(2048, 4), 256, 0, stream>>>(Sc, P);
  kpv<<<dim3(128, 4), 256, 0, stream>>>(P, Vt, Out);
}

// Round 11
// 140.806 us; speedup vs baseline: 1.5767x; 1.0488x over previous
//
#include <hip/hip_runtime.h>
#include <hip/hip_fp16.h>

typedef unsigned short u16;
typedef __attribute__((ext_vector_type(8))) short short8;
typedef __attribute__((ext_vector_type(4))) float f32x4;
typedef __attribute__((ext_vector_type(4))) unsigned short u16x4;
typedef __attribute__((ext_vector_type(4))) float float4v;

__device__ __forceinline__ u16 f2bf(float f) {
  union { float f; unsigned u; } v; v.f = f;
  unsigned r = v.u + 0x7FFFu + ((v.u >> 16) & 1u);
  return (u16)(r >> 16);
}

__device__ __forceinline__ u16 f2h(float f) {
  __half h = __float2half(f);
  return *reinterpret_cast<u16*>(&h);
}

__device__ __forceinline__ float h2f(u16 b) {
  __half_raw hr; hr.x = b;
  return __half2float(__half(hr));
}

__device__ __forceinline__ void gload16(const void* g, void* l) {
  __builtin_amdgcn_global_load_lds(
      (const __attribute__((address_space(1))) unsigned int*)g,
      (__attribute__((address_space(3))) unsigned int*)l, 16, 0, 0);
}

// ---------------- merged conversion kernel ----------------
// bx < 8192: X fp32 -> bf16 linear.  bx >= 8192: W -> Wt bf16 transposed.
__global__ __launch_bounds__(256) void kconv(const float* __restrict__ X,
                                             const float* __restrict__ Wq,
                                             const float* __restrict__ Wk,
                                             const float* __restrict__ Wv,
                                             u16* __restrict__ Xb,
                                             u16* __restrict__ Wt) {
  __shared__ float tile[32][33];
  const int bx = blockIdx.x;
  if (bx < 8192) {
    size_t i = ((size_t)bx * 256 + threadIdx.x) * 4;
    float4v v = *(const float4v*)(X + i);
    u16x4 o;
    o.x = f2bf(v.x); o.y = f2bf(v.y); o.z = f2bf(v.z); o.w = f2bf(v.w);
    *(u16x4*)(Xb + i) = o;
  } else {
    const int l = bx - 8192;          // 0..3071
    const int z = l >> 10;            // 0..2
    const int rem = l & 1023;         // 32x32 tiles
    const int n0 = (rem & 31) * 32, k0 = (rem >> 5) * 32;
    const float* W = z == 0 ? Wq : (z == 1 ? Wk : Wv);
    u16* O = Wt + (size_t)z * 1024 * 1024;
    const int tx = threadIdx.x & 31, ty = threadIdx.x >> 5;  // 32 x 8
#pragma unroll
    for (int r = 0; r < 32; r += 8)
      tile[ty + r][tx] = W[(size_t)(k0 + ty + r) * 1024 + n0 + tx];
    __syncthreads();
#pragma unroll
    for (int r = 0; r < 32; r += 8)
      O[(size_t)(n0 + ty + r) * 1024 + k0 + tx] = f2bf(tile[tx][ty + r]);
  }
}

// ---------------- GEMM core: BK=64, both-sides XOR swizzle ----------------
// C[128x128] += A[M,K] * Bt[N,K]^T ; 256 thr = 4 waves (2x2), 64x64/wave.
// LDS tiles [128][64] u16 (16KB each). Swizzle: LDS[row][s] holds global
// slot s^(row&7) (16B slots). gload_lds dest linear; source pre-swizzled;
// ds_read applies the same XOR -> worst 2-way bank aliasing (free).
__device__ __forceinline__ void stage64(const u16* __restrict__ pan, int ld,
                                        int k0, u16* dst, int t) {
  const int rb = t >> 3;                     // 0..31
  const int sw = ((t & 7) ^ (rb & 7)) * 8;   // pre-swizzled source slot
  const int ds = (t & 7) * 8;                // linear LDS slot
#pragma unroll
  for (int j = 0; j < 4; ++j) {
    const int row = j * 32 + rb;
    gload16(pan + (size_t)row * ld + k0 + sw, dst + row * 64 + ds);
  }
}

__device__ __forceinline__ void gemm64(const u16* __restrict__ A,
                                       const u16* __restrict__ B,
                                       int lda, int ldb,
                                       int rowBase, int colBase, int kIters,
                                       u16* As, u16* Bs, f32x4 acc[4][4]) {
  const int t = threadIdx.x;
  const int wid = t >> 6, lane = t & 63;
  const int wm = wid >> 1, wn = wid & 1;
  const int l15 = lane & 15;
  const int sw = l15 & 7;
  const int sl = lane >> 4;                  // 0..3
  const int s0 = ((sl    ) ^ sw) * 8;        // k 0..31 slot (u16 offset)
  const int s1 = ((sl + 4) ^ sw) * 8;        // k 32..63 slot
  const u16* ga = A + (size_t)rowBase * lda;
  const u16* gb = B + (size_t)colBase * ldb;

  for (int kt = 0; kt < kIters; ++kt) {
    const int k0 = kt * 64;
    stage64(ga, lda, k0, As, t);
    stage64(gb, ldb, k0, Bs, t);
    __syncthreads();
#pragma unroll
    for (int h = 0; h < 2; ++h) {
      const int so = h ? s1 : s0;
      short8 a[4], b[4];
#pragma unroll
      for (int mi = 0; mi < 4; mi++)
        a[mi] = *(const short8*)(As + (wm * 64 + mi * 16 + l15) * 64 + so);
#pragma unroll
      for (int ni = 0; ni < 4; ni++)
        b[ni] = *(const short8*)(Bs + (wn * 64 + ni * 16 + l15) * 64 + so);
#pragma unroll
      for (int mi = 0; mi < 4; mi++)
#pragma unroll
        for (int ni = 0; ni < 4; ni++)
          acc[mi][ni] = __builtin_amdgcn_mfma_f32_16x16x32_bf16(
              a[mi], b[ni], acc[mi][ni], 0, 0, 0);
    }
    __syncthreads();
  }
}

// ---------------- QKV projection ----------------
// 1536 blocks, XCD-chunked: XCD owns 8 row-tiles, (col,z) outer, row inner.
__global__ __launch_bounds__(256, 3) void kqkv(const u16* __restrict__ Xb,
                                               const u16* __restrict__ Wt,
                                               u16* __restrict__ Qb,
                                               u16* __restrict__ Kb,
                                               u16* __restrict__ Vt) {
  __shared__ __align__(16) u16 As[128 * 64];
  __shared__ __align__(16) u16 Bs[128 * 64];
  const f32x4 z4 = {0.f, 0.f, 0.f, 0.f};
  f32x4 acc[4][4];
#pragma unroll
  for (int i = 0; i < 4; i++)
#pragma unroll
    for (int j = 0; j < 4; j++) acc[i][j] = z4;

  const int l = blockIdx.x;
  const int xcd = l & 7, idx = l >> 3;     // idx 0..191
  const int cz = idx >> 3, rloc = idx & 7; // cz 0..23 outer, row inner
  const int rowTile = xcd * 8 + rloc;      // 0..63
  const int z = cz >> 3, colTile = cz & 7; // z 0..2, col 0..7

  const int rowBase = rowTile * 128, colBase = colTile * 128;
  const u16* Bt = Wt + (size_t)z * 1024 * 1024;
  gemm64(Xb, Bt, 1024, 1024, rowBase, colBase, 16, As, Bs, acc);

  const int t = threadIdx.x, wid = t >> 6, lane = t & 63;
  const int wm = wid >> 1, wn = wid & 1;
  const int r0 = rowBase + wm * 64 + ((lane >> 4) * 4);
  const int c0 = colBase + wn * 64 + (lane & 15);
  if (z < 2) {
    u16* O = z ? Kb : Qb;
#pragma unroll
    for (int mi = 0; mi < 4; mi++) {
      int r = r0 + mi * 16;
#pragma unroll
      for (int ni = 0; ni < 4; ni++) {
        int c = c0 + ni * 16;
#pragma unroll
        for (int j = 0; j < 4; j++)
          O[(size_t)(r + j) * 1024 + c] = f2bf(acc[mi][ni][j]);
      }
    }
  } else {
#pragma unroll
    for (int mi = 0; mi < 4; mi++) {
      int s0r = r0 + mi * 16;           // global row (= b*2048 + s)
      int bb = s0r >> 11, sl = s0r & 2047;
#pragma unroll
      for (int ni = 0; ni < 4; ni++) {
        int d = c0 + ni * 16;
        u16x4 pk;
        pk.x = f2bf(acc[mi][ni][0]);
        pk.y = f2bf(acc[mi][ni][1]);
        pk.z = f2bf(acc[mi][ni][2]);
        pk.w = f2bf(acc[mi][ni][3]);
        *(u16x4*)(Vt + ((size_t)bb * 1024 + d) * 2048 + sl) = pk;
      }
    }
  }
}

// ---------------- scores = Q K^T / 32 (lower-tri tiles, fp16 out) -----------
__global__ __launch_bounds__(256, 3) void kscores(const u16* __restrict__ Q,
                                                  const u16* __restrict__ K,
                                                  u16* __restrict__ Sch) {
  const int x = blockIdx.x, b = blockIdx.y;
  const int xcd = x & 7, idx = x >> 3;   // idx 0..16
  const int tid = xcd * 17 + idx;        // 0..135
  int tr = (int)((sqrtf(8.f * tid + 1.f) - 1.f) * 0.5f);
  while ((tr + 1) * (tr + 2) / 2 <= tid) ++tr;
  while (tr * (tr + 1) / 2 > tid) --tr;
  const int tc = tid - tr * (tr + 1) / 2;

  __shared__ __align__(16) u16 As[128 * 64];
  __shared__ __align__(16) u16 Bs[128 * 64];
  const f32x4 z4 = {0.f, 0.f, 0.f, 0.f};
  f32x4 acc[4][4];
#pragma unroll
  for (int i = 0; i < 4; i++)
#pragma unroll
    for (int j = 0; j < 4; j++) acc[i][j] = z4;

  const u16* Qp = Q + (size_t)b * 2048 * 1024;
  const u16* Kp = K + (size_t)b * 2048 * 1024;
  gemm64(Qp, Kp, 1024, 1024, tr * 128, tc * 128, 16, As, Bs, acc);

  u16* S = Sch + (size_t)b * 2048 * 2048;
  const int t = threadIdx.x, wid = t >> 6, lane = t & 63;
  const int wm = wid >> 1, wn = wid & 1;
  const int r0 = tr * 128 + wm * 64 + ((lane >> 4) * 4);
  const int c0 = tc * 128 + wn * 64 + (lane & 15);
#pragma unroll
  for (int mi = 0; mi < 4; mi++) {
    int r = r0 + mi * 16;
#pragma unroll
    for (int ni = 0; ni < 4; ni++) {
      int c = c0 + ni * 16;
#pragma unroll
      for (int j = 0; j < 4; j++)
        S[(size_t)(r + j) * 2048 + c] = f2h(acc[mi][ni][j] * 0.03125f);
    }
  }
}

// ---------------- row softmax (register-resident) -> P bf16 ----------------
// 256 thr x 8 elems = full 2048 row in regs; one 16B read, one 16B write.
// Masked lanes (c > i) produce exp(-inf)=0, so the causal zero-fill is free.
__global__ __launch_bounds__(256) void ksoftmax(const u16* __restrict__ Sch,
                                                u16* __restrict__ P) {
  const int i = blockIdx.x, b = blockIdx.y;
  const int t = threadIdx.x, lane = t & 63, wid = t >> 6;
  __shared__ float red[4];

  const size_t rowoff = ((size_t)b * 2048 + i) * 2048 + t * 8;
  short8 raw = *(const short8*)(Sch + rowoff);
  const int base = t * 8;
  float v[8];
#pragma unroll
  for (int k = 0; k < 8; ++k)
    v[k] = (base + k <= i) ? h2f((u16)raw[k]) : -3.0e38f;

  float lm = v[0];
#pragma unroll
  for (int k = 1; k < 8; ++k) lm = fmaxf(lm, v[k]);
#pragma unroll
  for (int o = 32; o > 0; o >>= 1) lm = fmaxf(lm, __shfl_down(lm, o));
  if (lane == 0) red[wid] = lm;
  __syncthreads();
  const float m = fmaxf(fmaxf(red[0], red[1]), fmaxf(red[2], red[3]));
  __syncthreads();  // everyone has m before red[] is reused

  float e[8], ls = 0.f;
#pragma unroll
  for (int k = 0; k < 8; ++k) {
    e[k] = __expf(fmaxf(v[k] - m, -88.f));
    ls += e[k];
  }
#pragma unroll
  for (int o = 32; o > 0; o >>= 1) ls += __shfl_down(ls, o);
  if (lane == 0) red[wid] = ls;
  __syncthreads();
  const float inv = 1.f / (red[0] + red[1] + red[2] + red[3]);

  short8 out;
#pragma unroll
  for (int k = 0; k < 8; ++k) out[k] = (short)f2bf(e[k] * inv);
  *(short8*)(P + rowoff) = out;
}

// ---------------- context = P V  (K-loop truncated causally) ----------------
__global__ __launch_bounds__(256, 3) void kpv(const u16* __restrict__ P,
                                              const u16* __restrict__ Vt,
                                              float* __restrict__ Out) {
  const int x = blockIdx.x, b = blockIdx.y;
  const int xcd = x & 7, idx = x >> 3;       // idx 0..15
  const int tr = (idx < 8) ? xcd : (15 - xcd);
  const int col = idx & 7;

  __shared__ __align__(16) u16 As[128 * 64];
  __shared__ __align__(16) u16 Bs[128 * 64];
  const f32x4 z4 = {0.f, 0.f, 0.f, 0.f};
  f32x4 acc[4][4];
#pragma unroll
  for (int i = 0; i < 4; i++)
#pragma unroll
    for (int j = 0; j < 4; j++) acc[i][j] = z4;

  const u16* Pp = P + (size_t)b * 2048 * 2048;
  const u16* Vp = Vt + (size_t)b * 1024 * 2048;
  gemm64(Pp, Vp, 2048, 2048, tr * 128, col * 128, (tr + 1) * 2, As, Bs, acc);

  float* Ob = Out + (size_t)b * 2048 * 1024;
  const int t = threadIdx.x, wid = t >> 6, lane = t & 63;
  const int wm = wid >> 1, wn = wid & 1;
  const int r0 = tr * 128 + wm * 64 + ((lane >> 4) * 4);
  const int c0 = col * 128 + wn * 64 + (lane & 15);
#pragma unroll
  for (int mi = 0; mi < 4; mi++) {
    int r = r0 + mi * 16;
#pragma unroll
    for (int ni = 0; ni < 4; ni++) {
      int c = c0 + ni * 16;
#pragma unroll
      for (int j = 0; j < 4; j++)
        Ob[(size_t)(r + j) * 1024 + c] = acc[mi][ni][j];
    }
  }
}

extern "C" void kernel_launch(void* const* d_in, const int* in_sizes, int n_in,
                              void* d_out, int out_size, void* d_ws,
                              size_t ws_size, hipStream_t stream) {
  const float* X = (const float*)d_in[0];
  const float* Wq = (const float*)d_in[1];
  const float* Wk = (const float*)d_in[2];
  const float* Wv = (const float*)d_in[3];
  float* Out = (float*)d_out;

  char* ws = (char*)d_ws;
  u16* Xb = (u16*)(ws);                     // 16 MB  bf16 X
  u16* Wt = (u16*)(ws + 16777216);          //  6 MB  bf16 W^T x3
  u16* Qb = (u16*)(ws + 23068672);          // 16 MB
  u16* Kb = (u16*)(ws + 39845888);          // 16 MB
  u16* Vt = (u16*)(ws + 56623104);          // 16 MB  V transposed per batch
  u16* Sch = (u16*)(ws + 73400320);         // 32 MB  fp16 scores
  u16* P = (u16*)(ws + 140509184);          // 32 MB  bf16 probs

  kconv<<<11264, 256, 0, stream>>>(X, Wq, Wk, Wv, Xb, Wt);
  kqkv<<<1536, 256, 0, stream>>>(Xb, Wt, Qb, Kb, Vt);
  kscores<<<dim3(136, 4), 256, 0, stream>>>(Qb, Kb, Sch);
  ksoftmax<<<dim3(2048, 4), 256, 0, stream>>>(Sch, P);
  kpv<<<dim3(128, 4), 256, 0, stream>>>(P, Vt, Out);
}

// Round 12
// 139.231 us; speedup vs baseline: 1.5945x; 1.0113x over previous
//
#include <hip/hip_runtime.h>
#include <hip/hip_fp16.h>

typedef unsigned short u16;
typedef __attribute__((ext_vector_type(8))) short short8;
typedef __attribute__((ext_vector_type(4))) float f32x4;
typedef __attribute__((ext_vector_type(4))) unsigned short u16x4;
typedef __attribute__((ext_vector_type(4))) float float4v;

__device__ __forceinline__ u16 f2bf(float f) {
  union { float f; unsigned u; } v; v.f = f;
  unsigned r = v.u + 0x7FFFu + ((v.u >> 16) & 1u);
  return (u16)(r >> 16);
}

__device__ __forceinline__ u16 f2h(float f) {
  __half h = __float2half(f);
  return *reinterpret_cast<u16*>(&h);
}

__device__ __forceinline__ float h2f(u16 b) {
  __half_raw hr; hr.x = b;
  return __half2float(__half(hr));
}

__device__ __forceinline__ void gload16(const void* g, void* l) {
  __builtin_amdgcn_global_load_lds(
      (const __attribute__((address_space(1))) unsigned int*)g,
      (__attribute__((address_space(3))) unsigned int*)l, 16, 0, 0);
}

// ---------------- merged conversion kernel ----------------
// bx < 8192: X fp32 -> bf16 linear.  bx >= 8192: W -> Wt bf16 transposed.
__global__ __launch_bounds__(256) void kconv(const float* __restrict__ X,
                                             const float* __restrict__ Wq,
                                             const float* __restrict__ Wk,
                                             const float* __restrict__ Wv,
                                             u16* __restrict__ Xb,
                                             u16* __restrict__ Wt) {
  __shared__ float tile[32][33];
  const int bx = blockIdx.x;
  if (bx < 8192) {
    size_t i = ((size_t)bx * 256 + threadIdx.x) * 4;
    float4v v = *(const float4v*)(X + i);
    u16x4 o;
    o.x = f2bf(v.x); o.y = f2bf(v.y); o.z = f2bf(v.z); o.w = f2bf(v.w);
    *(u16x4*)(Xb + i) = o;
  } else {
    const int l = bx - 8192;          // 0..3071
    const int z = l >> 10;            // 0..2
    const int rem = l & 1023;         // 32x32 tiles
    const int n0 = (rem & 31) * 32, k0 = (rem >> 5) * 32;
    const float* W = z == 0 ? Wq : (z == 1 ? Wk : Wv);
    u16* O = Wt + (size_t)z * 1024 * 1024;
    const int tx = threadIdx.x & 31, ty = threadIdx.x >> 5;  // 32 x 8
#pragma unroll
    for (int r = 0; r < 32; r += 8)
      tile[ty + r][tx] = W[(size_t)(k0 + ty + r) * 1024 + n0 + tx];
    __syncthreads();
#pragma unroll
    for (int r = 0; r < 32; r += 8)
      O[(size_t)(n0 + ty + r) * 1024 + k0 + tx] = f2bf(tile[tx][ty + r]);
  }
}

// ---------------- GEMM core: BK=64, both-sides XOR swizzle ----------------
// C[128x128] += A[M,K] * Bt[N,K]^T ; 256 thr = 4 waves (2x2), 64x64/wave.
// LDS tiles [128][64] u16 (16KB each). Swizzle: LDS[row][s] holds global
// slot s^(row&7) (16B slots). gload_lds dest linear; source pre-swizzled;
// ds_read applies the same XOR -> worst 2-way bank aliasing (free).
__device__ __forceinline__ void stage64(const u16* __restrict__ pan, int ld,
                                        int k0, u16* dst, int t) {
  const int rb = t >> 3;                     // 0..31
  const int sw = ((t & 7) ^ (rb & 7)) * 8;   // pre-swizzled source slot
  const int ds = (t & 7) * 8;                // linear LDS slot
#pragma unroll
  for (int j = 0; j < 4; ++j) {
    const int row = j * 32 + rb;
    gload16(pan + (size_t)row * ld + k0 + sw, dst + row * 64 + ds);
  }
}

__device__ __forceinline__ void gemm64(const u16* __restrict__ A,
                                       const u16* __restrict__ B,
                                       int lda, int ldb,
                                       int rowBase, int colBase, int kIters,
                                       u16* As, u16* Bs, f32x4 acc[4][4]) {
  const int t = threadIdx.x;
  const int wid = t >> 6, lane = t & 63;
  const int wm = wid >> 1, wn = wid & 1;
  const int l15 = lane & 15;
  const int sw = l15 & 7;
  const int sl = lane >> 4;                  // 0..3
  const int s0 = ((sl    ) ^ sw) * 8;        // k 0..31 slot (u16 offset)
  const int s1 = ((sl + 4) ^ sw) * 8;        // k 32..63 slot
  const u16* ga = A + (size_t)rowBase * lda;
  const u16* gb = B + (size_t)colBase * ldb;

  for (int kt = 0; kt < kIters; ++kt) {
    const int k0 = kt * 64;
    stage64(ga, lda, k0, As, t);
    stage64(gb, ldb, k0, Bs, t);
    __syncthreads();
#pragma unroll
    for (int h = 0; h < 2; ++h) {
      const int so = h ? s1 : s0;
      short8 a[4], b[4];
#pragma unroll
      for (int mi = 0; mi < 4; mi++)
        a[mi] = *(const short8*)(As + (wm * 64 + mi * 16 + l15) * 64 + so);
#pragma unroll
      for (int ni = 0; ni < 4; ni++)
        b[ni] = *(const short8*)(Bs + (wn * 64 + ni * 16 + l15) * 64 + so);
#pragma unroll
      for (int mi = 0; mi < 4; mi++)
#pragma unroll
        for (int ni = 0; ni < 4; ni++)
          acc[mi][ni] = __builtin_amdgcn_mfma_f32_16x16x32_bf16(
              a[mi], b[ni], acc[mi][ni], 0, 0, 0);
    }
    __syncthreads();
  }
}

// ---------------- QKV projection ----------------
// 1536 blocks, XCD-chunked: XCD owns 8 row-tiles, (col,z) outer, row inner.
__global__ __launch_bounds__(256, 3) void kqkv(const u16* __restrict__ Xb,
                                               const u16* __restrict__ Wt,
                                               u16* __restrict__ Qb,
                                               u16* __restrict__ Kb,
                                               u16* __restrict__ Vt) {
  __shared__ __align__(16) u16 As[128 * 64];
  __shared__ __align__(16) u16 Bs[128 * 64];
  const f32x4 z4 = {0.f, 0.f, 0.f, 0.f};
  f32x4 acc[4][4];
#pragma unroll
  for (int i = 0; i < 4; i++)
#pragma unroll
    for (int j = 0; j < 4; j++) acc[i][j] = z4;

  const int l = blockIdx.x;
  const int xcd = l & 7, idx = l >> 3;     // idx 0..191
  const int cz = idx >> 3, rloc = idx & 7; // cz 0..23 outer, row inner
  const int rowTile = xcd * 8 + rloc;      // 0..63
  const int z = cz >> 3, colTile = cz & 7; // z 0..2, col 0..7

  const int rowBase = rowTile * 128, colBase = colTile * 128;
  const u16* Bt = Wt + (size_t)z * 1024 * 1024;
  gemm64(Xb, Bt, 1024, 1024, rowBase, colBase, 16, As, Bs, acc);

  const int t = threadIdx.x, wid = t >> 6, lane = t & 63;
  const int wm = wid >> 1, wn = wid & 1;
  const int r0 = rowBase + wm * 64 + ((lane >> 4) * 4);
  const int c0 = colBase + wn * 64 + (lane & 15);
  if (z < 2) {
    u16* O = z ? Kb : Qb;
#pragma unroll
    for (int mi = 0; mi < 4; mi++) {
      int r = r0 + mi * 16;
#pragma unroll
      for (int ni = 0; ni < 4; ni++) {
        int c = c0 + ni * 16;
#pragma unroll
        for (int j = 0; j < 4; j++)
          O[(size_t)(r + j) * 1024 + c] = f2bf(acc[mi][ni][j]);
      }
    }
  } else {
#pragma unroll
    for (int mi = 0; mi < 4; mi++) {
      int s0r = r0 + mi * 16;           // global row (= b*2048 + s)
      int bb = s0r >> 11, sl = s0r & 2047;
#pragma unroll
      for (int ni = 0; ni < 4; ni++) {
        int d = c0 + ni * 16;
        u16x4 pk;
        pk.x = f2bf(acc[mi][ni][0]);
        pk.y = f2bf(acc[mi][ni][1]);
        pk.z = f2bf(acc[mi][ni][2]);
        pk.w = f2bf(acc[mi][ni][3]);
        *(u16x4*)(Vt + ((size_t)bb * 1024 + d) * 2048 + sl) = pk;
      }
    }
  }
}

// ---------------- scores = Q K^T / 32 (lower-tri tiles, fp16 out) -----------
__global__ __launch_bounds__(256, 3) void kscores(const u16* __restrict__ Q,
                                                  const u16* __restrict__ K,
                                                  u16* __restrict__ Sch) {
  const int x = blockIdx.x, b = blockIdx.y;
  const int xcd = x & 7, idx = x >> 3;   // idx 0..16
  const int tid = xcd * 17 + idx;        // 0..135
  int tr = (int)((sqrtf(8.f * tid + 1.f) - 1.f) * 0.5f);
  while ((tr + 1) * (tr + 2) / 2 <= tid) ++tr;
  while (tr * (tr + 1) / 2 > tid) --tr;
  const int tc = tid - tr * (tr + 1) / 2;

  __shared__ __align__(16) u16 As[128 * 64];
  __shared__ __align__(16) u16 Bs[128 * 64];
  const f32x4 z4 = {0.f, 0.f, 0.f, 0.f};
  f32x4 acc[4][4];
#pragma unroll
  for (int i = 0; i < 4; i++)
#pragma unroll
    for (int j = 0; j < 4; j++) acc[i][j] = z4;

  const u16* Qp = Q + (size_t)b * 2048 * 1024;
  const u16* Kp = K + (size_t)b * 2048 * 1024;
  gemm64(Qp, Kp, 1024, 1024, tr * 128, tc * 128, 16, As, Bs, acc);

  u16* S = Sch + (size_t)b * 2048 * 2048;
  const int t = threadIdx.x, wid = t >> 6, lane = t & 63;
  const int wm = wid >> 1, wn = wid & 1;
  const int r0 = tr * 128 + wm * 64 + ((lane >> 4) * 4);
  const int c0 = tc * 128 + wn * 64 + (lane & 15);
#pragma unroll
  for (int mi = 0; mi < 4; mi++) {
    int r = r0 + mi * 16;
#pragma unroll
    for (int ni = 0; ni < 4; ni++) {
      int c = c0 + ni * 16;
#pragma unroll
      for (int j = 0; j < 4; j++)
        S[(size_t)(r + j) * 2048 + c] = f2h(acc[mi][ni][j] * 0.03125f);
    }
  }
}

// ---------------- row softmax (register-resident, nceil-bounded) ------------
// 256 thr x 8 elems; loads/stores only up to the 128-tile ceiling of the row
// (kpv never reads past it). Masked lanes contribute exp(-inf)=0.
__global__ __launch_bounds__(256) void ksoftmax(const u16* __restrict__ Sch,
                                                u16* __restrict__ P) {
  const int i = blockIdx.x, b = blockIdx.y;
  const int t = threadIdx.x, lane = t & 63, wid = t >> 6;
  const int nceil = ((i >> 7) + 1) << 7;
  __shared__ float red[4];

  const size_t rowoff = ((size_t)b * 2048 + i) * 2048 + t * 8;
  const int base = t * 8;
  short8 raw = {0, 0, 0, 0, 0, 0, 0, 0};
  if (base < nceil) raw = *(const short8*)(Sch + rowoff);
  float v[8];
#pragma unroll
  for (int k = 0; k < 8; ++k)
    v[k] = (base + k <= i) ? h2f((u16)raw[k]) : -3.0e38f;

  float lm = v[0];
#pragma unroll
  for (int k = 1; k < 8; ++k) lm = fmaxf(lm, v[k]);
#pragma unroll
  for (int o = 32; o > 0; o >>= 1) lm = fmaxf(lm, __shfl_down(lm, o));
  if (lane == 0) red[wid] = lm;
  __syncthreads();
  const float m = fmaxf(fmaxf(red[0], red[1]), fmaxf(red[2], red[3]));
  __syncthreads();  // everyone has m before red[] is reused

  float e[8], ls = 0.f;
#pragma unroll
  for (int k = 0; k < 8; ++k) {
    e[k] = __expf(fmaxf(v[k] - m, -88.f));
    ls += e[k];
  }
#pragma unroll
  for (int o = 32; o > 0; o >>= 1) ls += __shfl_down(ls, o);
  if (lane == 0) red[wid] = ls;
  __syncthreads();
  const float inv = 1.f / (red[0] + red[1] + red[2] + red[3]);

  if (base < nceil) {
    short8 out;
#pragma unroll
    for (int k = 0; k < 8; ++k) out[k] = (short)f2bf(e[k] * inv);
    *(short8*)(P + rowoff) = out;
  }
}

// ---------------- context = P V  (K-loop truncated causally) ----------------
// Pairing: consecutive blocks (idx even/odd) take tr = xcd and 15-xcd, so any
// CU holding a consecutive pair gets a constant 17 k-units -> balanced.
__global__ __launch_bounds__(256, 3) void kpv(const u16* __restrict__ P,
                                              const u16* __restrict__ Vt,
                                              float* __restrict__ Out) {
  const int x = blockIdx.x, b = blockIdx.y;
  const int xcd = x & 7, idx = x >> 3;       // idx 0..15
  const int tr = (idx & 1) ? (15 - xcd) : xcd;
  const int col = idx >> 1;                  // 0..7

  __shared__ __align__(16) u16 As[128 * 64];
  __shared__ __align__(16) u16 Bs[128 * 64];
  const f32x4 z4 = {0.f, 0.f, 0.f, 0.f};
  f32x4 acc[4][4];
#pragma unroll
  for (int i = 0; i < 4; i++)
#pragma unroll
    for (int j = 0; j < 4; j++) acc[i][j] = z4;

  const u16* Pp = P + (size_t)b * 2048 * 2048;
  const u16* Vp = Vt + (size_t)b * 1024 * 2048;
  gemm64(Pp, Vp, 2048, 2048, tr * 128, col * 128, (tr + 1) * 2, As, Bs, acc);

  float* Ob = Out + (size_t)b * 2048 * 1024;
  const int t = threadIdx.x, wid = t >> 6, lane = t & 63;
  const int wm = wid >> 1, wn = wid & 1;
  const int r0 = tr * 128 + wm * 64 + ((lane >> 4) * 4);
  const int c0 = col * 128 + wn * 64 + (lane & 15);
#pragma unroll
  for (int mi = 0; mi < 4; mi++) {
    int r = r0 + mi * 16;
#pragma unroll
    for (int ni = 0; ni < 4; ni++) {
      int c = c0 + ni * 16;
#pragma unroll
      for (int j = 0; j < 4; j++)
        Ob[(size_t)(r + j) * 1024 + c] = acc[mi][ni][j];
    }
  }
}

extern "C" void kernel_launch(void* const* d_in, const int* in_sizes, int n_in,
                              void* d_out, int out_size, void* d_ws,
                              size_t ws_size, hipStream_t stream) {
  const float* X = (const float*)d_in[0];
  const float* Wq = (const float*)d_in[1];
  const float* Wk = (const float*)d_in[2];
  const float* Wv = (const float*)d_in[3];
  float* Out = (float*)d_out;

  char* ws = (char*)d_ws;
  u16* Xb = (u16*)(ws);                     // 16 MB  bf16 X
  u16* Wt = (u16*)(ws + 16777216);          //  6 MB  bf16 W^T x3
  u16* Qb = (u16*)(ws + 23068672);          // 16 MB
  u16* Kb = (u16*)(ws + 39845888);          // 16 MB
  u16* Vt = (u16*)(ws + 56623104);          // 16 MB  V transposed per batch
  u16* Sch = (u16*)(ws + 73400320);         // 32 MB  fp16 scores
  u16* P = (u16*)(ws + 140509184);          // 32 MB  bf16 probs

  kconv<<<11264, 256, 0, stream>>>(X, Wq, Wk, Wv, Xb, Wt);
  kqkv<<<1536, 256, 0, stream>>>(Xb, Wt, Qb, Kb, Vt);
  kscores<<<dim3(136, 4), 256, 0, stream>>>(Qb, Kb, Sch);
  ksoftmax<<<dim3(2048, 4), 256, 0, stream>>>(Sch, P);
  kpv<<<dim3(128, 4), 256, 0, stream>>>(P, Vt, Out);
}